// Round 4
// baseline (7121.903 us; speedup 1.0000x reference)
//
#include <hip/hip_runtime.h>
#include <hip/hip_bf16.h>

#define BB 8
#define NN 1024
#define DD 768
#define HH 12
#define DKVX 64
#define DFF 3072
#define EE 16
#define CAPX 128
#define NT (BB*NN)   // 8192 tokens

__device__ __forceinline__ float b2f(__hip_bfloat16 x) { return __bfloat162float(x); }
__device__ __forceinline__ __hip_bfloat16 f2b(float x) { return __float2bfloat16(x); }
__device__ __forceinline__ float toFloat(float x) { return x; }
__device__ __forceinline__ float toFloat(__hip_bfloat16 x) { return __bfloat162float(x); }

// ---- 8-element vector loads (16B for bf16, 32B for float) ----
__device__ __forceinline__ void load8(const __hip_bfloat16* p, float* dst) {
    uint4 u = *reinterpret_cast<const uint4*>(p);
    const __hip_bfloat16* hb = reinterpret_cast<const __hip_bfloat16*>(&u);
#pragma unroll
    for (int i = 0; i < 8; ++i) dst[i] = b2f(hb[i]);
}
__device__ __forceinline__ void load8(const float* p, float* dst) {
    float4 a = reinterpret_cast<const float4*>(p)[0];
    float4 b = reinterpret_cast<const float4*>(p)[1];
    dst[0]=a.x; dst[1]=a.y; dst[2]=a.z; dst[3]=a.w;
    dst[4]=b.x; dst[5]=b.y; dst[6]=b.z; dst[7]=b.w;
}
__device__ __forceinline__ void storeC(float* p, float v) { *p = v; }
__device__ __forceinline__ void storeC(__hip_bfloat16* p, float v) { *p = f2b(v); }

// ---- RMSNorm (T5): out fp32 = x * rsqrt(mean(x^2)+1e-6) * w ----
template<typename TIN>
__global__ __launch_bounds__(256) void rmsnorm_k(const TIN* __restrict__ x,
                                                 const float* __restrict__ w,
                                                 float* __restrict__ out) {
    int t = blockIdx.x;
    int tid = threadIdx.x;
    const TIN* xp = x + (size_t)t * DD;
    float xv[3];
    float s = 0.f;
#pragma unroll
    for (int i = 0; i < 3; ++i) {
        float v = toFloat(xp[tid + i*256]);
        xv[i] = v; s += v*v;
    }
#pragma unroll
    for (int off = 1; off < 64; off <<= 1) s += __shfl_xor(s, off);
    __shared__ float sm[8];
    int wv = tid >> 6, ln = tid & 63;
    if (ln == 0) sm[wv] = s;
    __syncthreads();
    if (tid == 0) {
        float tot = sm[0]+sm[1]+sm[2]+sm[3];
        sm[4] = 1.0f / sqrtf(tot / (float)DD + 1e-6f);
    }
    __syncthreads();
    float sc = sm[4];
    float* op = out + (size_t)t * DD;
#pragma unroll
    for (int i = 0; i < 3; ++i) {
        int d = tid + i*256;
        op[d] = xv[i] * sc * w[d];
    }
}

// ---- Generic tiled GEMM: C[M,N] = A[M,K] @ B[K,N]; fp32 accum.
// 128x128 tile, BK=16, 256 threads, 8x8 per thread. batch via blockIdx.z.
template<typename TA, typename TB, typename TC, bool RELU, bool RESID>
__global__ __launch_bounds__(256) void gemm_k(const TA* __restrict__ A,
                                              const TB* __restrict__ B,
                                              TC* __restrict__ C,
                                              const float* __restrict__ R,
                                              int M, int N, int K,
                                              long sA, long sB, long sC) {
    __shared__ float As[16][132];
    __shared__ float Bs[16][132];
    const int bz = blockIdx.z;
    A += (size_t)bz * sA; B += (size_t)bz * sB; C += (size_t)bz * sC;
    const int row0 = blockIdx.y * 128, col0 = blockIdx.x * 128;
    const int tid = threadIdx.x;
    const int tx = tid & 15, ty = tid >> 4;
    const int ar = tid >> 1, ak = (tid & 1) * 8;   // A loader: row, k-offset
    const int bk = tid >> 4, bc = (tid & 15) * 8;  // B loader: k-row, col-offset
    float acc[8][8] = {};
    for (int k0 = 0; k0 < K; k0 += 16) {
        float av[8], bv[8];
        load8(A + (size_t)(row0 + ar) * K + (k0 + ak), av);
        load8(B + (size_t)(k0 + bk) * N + (col0 + bc), bv);
#pragma unroll
        for (int j = 0; j < 8; ++j) As[ak + j][ar] = av[j];
#pragma unroll
        for (int j = 0; j < 8; ++j) Bs[bk][bc + j] = bv[j];
        __syncthreads();
#pragma unroll
        for (int kk = 0; kk < 16; ++kk) {
            float a[8], b[8];
#pragma unroll
            for (int i = 0; i < 8; ++i) a[i] = As[kk][ty*8 + i];
#pragma unroll
            for (int j = 0; j < 8; ++j) b[j] = Bs[kk][tx*8 + j];
#pragma unroll
            for (int i = 0; i < 8; ++i)
#pragma unroll
                for (int j = 0; j < 8; ++j)
                    acc[i][j] += a[i] * b[j];
        }
        __syncthreads();
    }
#pragma unroll
    for (int i = 0; i < 8; ++i) {
        int r = row0 + ty*8 + i;
#pragma unroll
        for (int j = 0; j < 8; ++j) {
            int c = col0 + tx*8 + j;
            float v = acc[i][j];
            if (RESID) v += R[(size_t)r * N + c];
            if (RELU)  v = fmaxf(v, 0.f);
            storeC(C + (size_t)r * N + c, v);
        }
    }
}

// ---- Attention: one wave per (b,h,query row). No scaling (T5), mask all-true.
__global__ __launch_bounds__(256) void attn_k(const float* __restrict__ q,
                                              const float* __restrict__ k,
                                              const float* __restrict__ v,
                                              float* __restrict__ ctx) {
    __shared__ float sc[4][NN];
    __shared__ float qs[4][DKVX];
    int wave = threadIdx.x >> 6, lane = threadIdx.x & 63;
    int blk = blockIdx.x;
    int qt = blk & 255; int bh = blk >> 8;
    int h = bh % HH; int b = bh / HH;
    int qi = qt * 4 + wave;
    size_t base = (size_t)b * NN * DD + (size_t)h * DKVX;
    qs[wave][lane] = q[base + (size_t)qi * DD + lane];
    __syncthreads();
    float m = -1e30f;
    float sv[16];
#pragma unroll
    for (int it = 0; it < 16; ++it) {
        int j = lane + it * 64;
        const float4* kp = (const float4*)(k + base + (size_t)j * DD);
        float s = 0.f;
#pragma unroll
        for (int d4 = 0; d4 < 16; ++d4) {
            float4 kv = kp[d4];
            s += qs[wave][d4*4+0]*kv.x + qs[wave][d4*4+1]*kv.y
               + qs[wave][d4*4+2]*kv.z + qs[wave][d4*4+3]*kv.w;
        }
        sv[it] = s;
        m = fmaxf(m, s);
    }
#pragma unroll
    for (int off = 1; off < 64; off <<= 1) m = fmaxf(m, __shfl_xor(m, off));
    float ssum = 0.f;
#pragma unroll
    for (int it = 0; it < 16; ++it) {
        float e = expf(sv[it] - m);
        sc[wave][lane + it*64] = e;
        ssum += e;
    }
#pragma unroll
    for (int off = 1; off < 64; off <<= 1) ssum += __shfl_xor(ssum, off);
    float inv = 1.0f / ssum;
    __syncthreads();
    float acc = 0.f;
    const float* vp = v + base + lane;
#pragma unroll 8
    for (int j = 0; j < NN; ++j) {
        acc += sc[wave][j] * vp[(size_t)j * DD];
    }
    ctx[base + (size_t)qi * DD + lane] = acc * inv;
}

// ---- Gate: logits -> softmax -> top2 (+normalized gates), proxy/density accum
__global__ __launch_bounds__(256) void gate_k(const float* __restrict__ x,
                                              const float* __restrict__ gw,
                                              int* __restrict__ idx1, int* __restrict__ idx2,
                                              float* __restrict__ g1n, float* __restrict__ g2n,
                                              float* __restrict__ proxy, float* __restrict__ cnt1) {
    __shared__ float gws[DD*EE];
    for (int i = threadIdx.x; i < DD*EE; i += 256) gws[i] = gw[i];
    __syncthreads();
    int t = blockIdx.x * 256 + threadIdx.x;
    int b = t >> 10;
    float acc[EE] = {};
    const float4* xp = (const float4*)(x + (size_t)t * DD);
    for (int d4 = 0; d4 < DD/4; ++d4) {
        float4 xv = xp[d4];
        float xs[4] = {xv.x, xv.y, xv.z, xv.w};
#pragma unroll
        for (int qq = 0; qq < 4; ++qq) {
            const float* g = &gws[(d4*4+qq)*EE];
#pragma unroll
            for (int e = 0; e < EE; ++e) acc[e] += xs[qq] * g[e];
        }
    }
    // softmax over 16
    float m = acc[0];
#pragma unroll
    for (int e = 1; e < EE; ++e) m = fmaxf(m, acc[e]);
    float sum = 0.f;
    float raw[EE];
#pragma unroll
    for (int e = 0; e < EE; ++e) { raw[e] = expf(acc[e] - m); sum += raw[e]; }
    float inv = 1.0f / sum;
#pragma unroll
    for (int e = 0; e < EE; ++e) raw[e] *= inv;
    // top-1 (first occurrence on ties, like jnp.argmax)
    int i1 = 0; float p1 = raw[0];
#pragma unroll
    for (int e = 1; e < EE; ++e) if (raw[e] > p1) { p1 = raw[e]; i1 = e; }
    // top-2 among the rest
    int i2 = (i1 == 0) ? 1 : 0; float p2 = raw[i2];
#pragma unroll
    for (int e = 0; e < EE; ++e) if (e != i1 && raw[e] > p2) { p2 = raw[e]; i2 = e; }
    float den = p1 + p2 + 1e-9f;
    idx1[t] = i1; idx2[t] = i2;
    g1n[t] = p1 / den; g2n[t] = p2 / den;
    // wave-reduced atomics: proxy (softmax sums) and density counts
    int ln = threadIdx.x & 63;
#pragma unroll
    for (int e = 0; e < EE; ++e) {
        float r = raw[e];
#pragma unroll
        for (int off = 1; off < 64; off <<= 1) r += __shfl_xor(r, off);
        if (ln == 0) atomicAdd(&proxy[b*EE + e], r);
    }
#pragma unroll
    for (int e = 0; e < EE; ++e) {
        unsigned long long mb = __ballot(i1 == e);
        if (ln == 0 && mb) atomicAdd(&cnt1[b*EE + e], (float)__popcll(mb));
    }
}

// ---- Capacity: literal sequential scan per (b,e). 128 threads total.
__global__ void capacity_k(const int* __restrict__ idx1, const int* __restrict__ idx2,
                           const float* __restrict__ g1n, const float* __restrict__ g2n,
                           float* __restrict__ g1k, float* __restrict__ g2k,
                           int* __restrict__ pos1, int* __restrict__ pos2,
                           int* __restrict__ tokslot) {
    int th = blockIdx.x * blockDim.x + threadIdx.x;
    if (th >= BB*EE) return;
    int b = th >> 4, e = th & 15;
    int base = b * NN;
    int c1 = 0;
    for (int n = 0; n < NN; ++n) {
        int t = base + n;
        if (idx1[t] == e) {
            if (c1 < CAPX) {
                g1k[t] = g1n[t]; pos1[t] = c1;
                tokslot[(e*BB + b)*CAPX + c1] = t;
            } else { g1k[t] = 0.f; pos1[t] = 0; }
            c1++;
        }
    }
    int m1c = c1 < CAPX ? c1 : CAPX;
    int c2 = 0;
    for (int n = 0; n < NN; ++n) {
        int t = base + n;
        if (idx2[t] == e) {
            int p = c2 + m1c;
            if (p < CAPX) {
                g2k[t] = g2n[t]; pos2[t] = p;
                tokslot[(e*BB + b)*CAPX + p] = t;
            } else { g2k[t] = 0.f; pos2[t] = 0; }
            c2++;
        }
    }
}

// ---- Gather tokens into expert slots (zero-fill empty slots) ----
__global__ __launch_bounds__(256) void gather_k(const float* __restrict__ x,
                                                const int* __restrict__ tokslot,
                                                __hip_bfloat16* __restrict__ xin) {
    int sid = blockIdx.x;
    int t = tokslot[sid];
    __hip_bfloat16* op = xin + (size_t)sid * DD;
    if (t >= 0) {
        const float* xp = x + (size_t)t * DD;
        for (int d = threadIdx.x; d < DD; d += 256) op[d] = f2b(xp[d]);
    } else {
        for (int d = threadIdx.x; d < DD; d += 256) op[d] = f2b(0.f);
    }
}

// ---- Final combine: out(fp32) = h + g1*xo[e1,slot1] + g2*xo[e2,slot2] ----
__global__ __launch_bounds__(256) void combine_k(const float* __restrict__ h,
                                                 const __hip_bfloat16* __restrict__ xo,
                                                 const int* __restrict__ idx1, const int* __restrict__ idx2,
                                                 const int* __restrict__ pos1, const int* __restrict__ pos2,
                                                 const float* __restrict__ g1k, const float* __restrict__ g2k,
                                                 float* __restrict__ out) {
    int t = blockIdx.x;
    int b = t >> 10;
    float ga = g1k[t], gb = g2k[t];
    const __hip_bfloat16* xa = nullptr;
    const __hip_bfloat16* xb = nullptr;
    if (ga > 0.f) xa = xo + (size_t)((idx1[t]*BB + b)*CAPX + pos1[t]) * DD;
    if (gb > 0.f) xb = xo + (size_t)((idx2[t]*BB + b)*CAPX + pos2[t]) * DD;
    const float* hp = h + (size_t)t * DD;
    float* op = out + (size_t)t * DD;
    for (int d = threadIdx.x; d < DD; d += 256) {
        float v = hp[d];
        if (xa) v += ga * b2f(xa[d]);
        if (xb) v += gb * b2f(xb[d]);
        op[d] = v;
    }
}

// ---- Aux loss: mean(proxy*density)*E*E*coef -> fp32 scalar ----
__global__ void loss_k(const float* __restrict__ proxy, const float* __restrict__ cnt1,
                       float* __restrict__ out_loss) {
    int tid = threadIdx.x; // 128 threads, one per (b,e)
    float v = proxy[tid] * cnt1[tid];
#pragma unroll
    for (int off = 1; off < 64; off <<= 1) v += __shfl_xor(v, off);
    __shared__ float sm[2];
    if ((tid & 63) == 0) sm[tid >> 6] = v;
    __syncthreads();
    if (tid == 0) {
        float tot = sm[0] + sm[1];
        // loss = [sum_{b,e} (proxy/N)*(cnt/N)] / (B*E) * E*E * 0.01
        float loss = tot * (0.02f / (1024.f * 1024.f));
        *out_loss = loss;
    }
}

extern "C" void kernel_launch(void* const* d_in, const int* in_sizes, int n_in,
                              void* d_out, int out_size, void* d_ws, size_t ws_size,
                              hipStream_t stream) {
    // Inputs are float32 (reference dtype); OUTPUT is float32 (reference output dtype).
    const float* hid = (const float*)d_in[0];
    // d_in[1] = attention_mask (all-true) -> bias 0 -> unused
    const float* ln0 = (const float*)d_in[2];
    const float* Wq  = (const float*)d_in[3];
    const float* Wk  = (const float*)d_in[4];
    const float* Wv  = (const float*)d_in[5];
    const float* Wo  = (const float*)d_in[6];
    const float* ln1 = (const float*)d_in[7];
    const float* gw  = (const float*)d_in[8];
    const float* w1  = (const float*)d_in[9];
    const float* w2  = (const float*)d_in[10];
    float* out = (float*)d_out;

    // ---- Workspace with static liveness-based overlap (total ~176.5 MB) ----
    // SZ = one fp32 token-buffer = NT*DD*4 = 25,165,824 B (256-aligned)
    //   bufA: normed -> ctxf -> hffn[0:SZ)
    //   bufB: qf            -> hffn[SZ:2SZ)
    //   bufC: kf            -> hffn[2SZ:3SZ)
    //   bufD: vf            -> hffn[3SZ:4SZ)   (hffn bf16 = 4*SZ exactly)
    //   hres: live to the end
    //   bufF: normed2 -> xo (bf16)
    const size_t SZ = (size_t)NT * DD * 4;
    char* p = (char*)d_ws;
    auto alloc = [&](size_t bytes) { char* r = p; p += (bytes + 255) & ~(size_t)255; return (void*)r; };
    float* bufA = (float*)alloc(SZ);
    float* bufB = (float*)alloc(SZ);
    float* bufC = (float*)alloc(SZ);
    float* bufD = (float*)alloc(SZ);
    float* hres = (float*)alloc(SZ);
    float* bufF = (float*)alloc(SZ);
    __hip_bfloat16* xin = (__hip_bfloat16*)alloc((size_t)EE*BB*CAPX*DD*2);
    int*   idx1 = (int*)alloc(NT*4);
    int*   idx2 = (int*)alloc(NT*4);
    float* g1n  = (float*)alloc(NT*4);
    float* g2n  = (float*)alloc(NT*4);
    float* g1k  = (float*)alloc(NT*4);
    float* g2k  = (float*)alloc(NT*4);
    int*   pos1 = (int*)alloc(NT*4);
    int*   pos2 = (int*)alloc(NT*4);
    int*   tokslot = (int*)alloc(EE*BB*CAPX*4);
    float* proxy   = (float*)alloc(BB*EE*4);
    float* cnt1f   = (float*)alloc(BB*EE*4);
    size_t needed = (size_t)(p - (char*)d_ws);
    if (needed > ws_size) return;  // out stays 0 -> absmax ~5.69 means "ws too small"

    float* normed  = bufA;
    float* qf      = bufB;
    float* kf      = bufC;
    float* vf      = bufD;
    float* ctxf    = bufA;                        // reuse: normed dead after QKV
    float* normed2 = bufF;
    __hip_bfloat16* hffn = (__hip_bfloat16*)bufA; // reuse: spans bufA..bufD = 4*SZ exactly
    __hip_bfloat16* xo   = (__hip_bfloat16*)bufF; // reuse: normed2 dead after gather

    (void)hipMemsetAsync(tokslot, 0xFF, EE*BB*CAPX*4, stream);
    (void)hipMemsetAsync(proxy, 0, BB*EE*4, stream);
    (void)hipMemsetAsync(cnt1f, 0, BB*EE*4, stream);

    // 1. RMSNorm(hidden)
    rmsnorm_k<float><<<NT, 256, 0, stream>>>(hid, ln0, normed);
    // 2. Q,K,V projections (all fp32: routing must match reference argmax)
    dim3 gqkv(DD/128, NT/128, 1);
    gemm_k<float,float,float,false,false><<<gqkv, 256, 0, stream>>>(normed, Wq, qf, nullptr, NT, DD, DD, 0,0,0);
    gemm_k<float,float,float,false,false><<<gqkv, 256, 0, stream>>>(normed, Wk, kf, nullptr, NT, DD, DD, 0,0,0);
    gemm_k<float,float,float,false,false><<<gqkv, 256, 0, stream>>>(normed, Wv, vf, nullptr, NT, DD, DD, 0,0,0);
    // 3. Attention (unscaled, full softmax); writes ctxf (= bufA, normed now dead)
    attn_k<<<BB*HH*(NN/4), 256, 0, stream>>>(qf, kf, vf, ctxf);
    // 4. O-projection + residual -> h (fp32)
    gemm_k<float,float,float,false,true><<<gqkv, 256, 0, stream>>>(ctxf, Wo, hres, hid, NT, DD, DD, 0,0,0);
    // 5. RMSNorm(h)
    rmsnorm_k<float><<<NT, 256, 0, stream>>>(hres, ln1, normed2);
    // 6. Gating
    gate_k<<<NT/256, 256, 0, stream>>>(normed2, gw, idx1, idx2, g1n, g2n, proxy, cnt1f);
    // 7. Capacity assignment (sequential per (b,e))
    capacity_k<<<2, 64, 0, stream>>>(idx1, idx2, g1n, g2n, g1k, g2k, pos1, pos2, tokslot);
    // 8. Gather into expert slots (fp32 -> bf16)
    gather_k<<<EE*BB*CAPX, 256, 0, stream>>>(normed2, tokslot, xin);
    // 9. Expert FFN: hffn = relu(xin @ w1)   (A bf16, B fp32, C bf16)
    dim3 gf1(DFF/128, (BB*CAPX)/128, EE);
    gemm_k<__hip_bfloat16,float,__hip_bfloat16,true,false><<<gf1, 256, 0, stream>>>(
        xin, w1, hffn, nullptr, BB*CAPX, DFF, DD,
        (long)BB*CAPX*DD, (long)DD*DFF, (long)BB*CAPX*DFF);
    // 10. Expert FFN: xo = hffn @ w2
    dim3 gf2(DD/128, (BB*CAPX)/128, EE);
    gemm_k<__hip_bfloat16,float,__hip_bfloat16,false,false><<<gf2, 256, 0, stream>>>(
        hffn, w2, xo, nullptr, BB*CAPX, DD, DFF,
        (long)BB*CAPX*DFF, (long)DFF*DD, (long)BB*CAPX*DD);
    // 11. Combine + residual -> output (fp32)
    combine_k<<<NT, 256, 0, stream>>>(hres, xo, idx1, idx2, pos1, pos2, g1k, g2k, out);
    // 12. Aux loss scalar (fp32)
    loss_k<<<1, 128, 0, stream>>>(proxy, cnt1f, out + (size_t)NT*DD);
}